// Round 14
// baseline (487.850 us; speedup 1.0000x reference)
//
#include <hip/hip_runtime.h>
#include <math.h>

// ---------------------------------------------------------------------------
// CapsuleNet forward. R33: fuse the routing chain. Routing is per-b
// independent (v[b] <- ssum[b] <- WU[b]), so one 512-thread block per b
// (32 groups x 16 lanes, 36 n/group) runs ALL of: red0 (= iteration 0 with
// c = softmax(0) = 0.1 exactly), routing iter 1, routing iter 2 — with LDS
// reductions + __syncthreads between iterations. Eliminates: zero_ssum_k,
// red0_k (94MB HBM re-read), both routing launches, all global atomics, and
// 3 launch gaps. ssum slot 2 written once (plain coalesced stores) for dec1.
// Same math as R32 (recompute-bij structure). 14 -> 11 launches.
// pc_mfma_k frozen at R28 best (105us, 7-variant plateau). Rest = R32 (482us).
// ---------------------------------------------------------------------------

typedef unsigned short u16;
typedef short bf16x8 __attribute__((ext_vector_type(8)));
typedef float f32x4 __attribute__((ext_vector_type(4)));

#define PS 2359296   // 9216*256, one y2 partial buffer
#define KSPLIT 9
#define KSLICE 2304  // 20736/9
#define NSTG2 18     // 2304/128

__device__ u16 g_x1b[256 * 400 * 256];          // conv1 out NHWC bf16 (52 MB)
__device__ u16 g_wbF[648 * 16 * 512];           // pc_w bf16, MFMA frag order (10.6 MB)
__device__ u16 g_y2p[(size_t)KSPLIT * PS];      // pc GEMM K-partials bf16 (42.5 MB)
__device__ float g_u[256 * 1152 * 8];           // squashed primary caps
__device__ u16 g_WU[(size_t)256 * 1152 * 160];  // u_hat bf16 (94.4 MB)
__device__ float g_ssum[3 * 256 * 160];         // only slot 2 used now
__device__ float g_h1[256 * 512];
__device__ float g_h2[256 * 1024];

// conv1-as-GEMM buffers
__device__ __attribute__((aligned(256))) u16 g_im2[(size_t)102400 * 104];  // im2col bf16, 104-padded rows (21.3 MB)
__device__ __attribute__((aligned(256))) u16 g_wb1[48 * 512];              // conv1_w frags (48 KB)

__device__ __forceinline__ u16 f2bf(float f) {
  union { float f; unsigned u; } v; v.f = f;
  unsigned r = (v.u + 0x7FFFu + ((v.u >> 16) & 1u)) >> 16;  // RNE
  return (u16)r;
}
__device__ __forceinline__ float bf2f(u16 h) {
  union { unsigned u; float f; } v; v.u = ((unsigned)h) << 16;
  return v.f;
}

// ------ pc_w fp32 [oc][ic][kp] -> bf16 16x16 fragment order (R25) ---------
__global__ __launch_bounds__(256) void wconv_k(const float* __restrict__ w) {
  __shared__ float Ws[16 * 648];   // [ocl][ic_local*81 + kp] 41.5 KB
  int n16 = blockIdx.x;   // 0..15
  int icb = blockIdx.y;   // 0..31
  int c = icb >> 2, h = icb & 3;
  int t = threadIdx.x;
#pragma unroll
  for (int ocl = 0; ocl < 16; ocl++) {
    const float* src = w + (size_t)(n16 * 16 + ocl) * 20736 + icb * 648;
    for (int i = t; i < 648; i += 256) Ws[ocl * 648 + i] = src[i];
  }
  __syncthreads();
  for (int wi = t; wi < 81 * 128; wi += 256) {
    int kp = wi >> 7;
    int r7 = wi & 127;
    int llh = r7 >> 3, j = wi & 7;
    g_wbF[(((size_t)kp * 8 + c) * 16 + n16) * 512 + h * 128 + r7] =
        f2bf(Ws[llh * 648 + j * 81 + kp]);
  }
}

// ------ conv1_w fp32 [oc][81] -> bf16 MFMA B-fragment order ----------------
__global__ __launch_bounds__(256) void wb1_k(const float* __restrict__ w) {
  int idx = blockIdx.x * 256 + threadIdx.x;   // 0..24575
  int frag = idx >> 9;     // kc*16 + n16
  int r = idx & 511;
  int ll = r >> 3, j = r & 7;
  int kc = frag >> 4, n16 = frag & 15;
  int k = kc * 32 + ((ll >> 4) << 3) + j;
  int oc = n16 * 16 + (ll & 15);
  float v = (k < 81) ? w[oc * 81 + k] : 0.f;
  g_wb1[idx] = f2bf(v);
}

// ------ im2col: input fp32 [b][28][28] -> bf16 patches [m][104] ------------
__global__ __launch_bounds__(256) void im2col_k(const float* __restrict__ in) {
  __shared__ u16 im_s[784];
  int b = blockIdx.x;
  int t = threadIdx.x;
  for (int i = t; i < 784; i += 256) im_s[i] = f2bf(in[b * 784 + i]);
  __syncthreads();
  u16* outp = g_im2 + (size_t)b * 41600;   // 400*104
  int base = blockIdx.y * 2600;            // octet halves (5200 octets/image)
  for (int ii = t; ii < 2600; ii += 256) {
    int idx = base + ii;
    int p = idx / 13;                      // pixel 0..399
    int ko = (idx - p * 13) * 8;           // 0,8,...,96
    int oy = p / 20, ox = p - oy * 20;
    bf16x8 v;
#pragma unroll
    for (int e = 0; e < 8; e++) {
      int k = ko + e;
      u16 x = 0;
      if (k < 81) {
        int ky = k / 9, kx = k - ky * 9;
        x = im_s[(oy + ky) * 28 + ox + kx];
      }
      v[e] = (short)x;
    }
    *(bf16x8*)(outp + (size_t)p * 104 + ko) = v;   // 16B aligned (208B rows)
  }
}

// ------ conv1 as MFMA GEMM: M=102400, N=256, K=96 --------------------------
__global__ __launch_bounds__(256) void conv1_mfma_k(const float* __restrict__ bias) {
  int t = threadIdx.x;
  int wq = t >> 6;          // wave's oc-quarter
  int l = t & 63;
  int q = l >> 4, c15 = l & 15;
  int m0 = blockIdx.x * 64;

  // B fragments: 3 kc x 4 n16 (this wave's quarter)
  bf16x8 bf[3][4];
#pragma unroll
  for (int kc = 0; kc < 3; kc++)
#pragma unroll
    for (int jn = 0; jn < 4; jn++)
      bf[kc][jn] = *(const bf16x8*)&g_wb1[((kc * 16 + wq * 4 + jn) << 9) + l * 8];

  // A fragments: 4 m-tiles x 3 kc
  bf16x8 af[4][3];
#pragma unroll
  for (int mt = 0; mt < 4; mt++) {
    const u16* ap = g_im2 + (size_t)(m0 + mt * 16 + c15) * 104 + q * 8;
#pragma unroll
    for (int kc = 0; kc < 3; kc++)
      af[mt][kc] = *(const bf16x8*)(ap + kc * 32);
  }

  f32x4 acc[4][4];
#pragma unroll
  for (int mt = 0; mt < 4; mt++)
#pragma unroll
    for (int jn = 0; jn < 4; jn++) acc[mt][jn] = (f32x4){0.f, 0.f, 0.f, 0.f};

#pragma unroll
  for (int kc = 0; kc < 3; kc++)
#pragma unroll
    for (int mt = 0; mt < 4; mt++)
#pragma unroll
      for (int jn = 0; jn < 4; jn++)
        acc[mt][jn] = __builtin_amdgcn_mfma_f32_16x16x32_bf16(af[mt][kc], bf[kc][jn], acc[mt][jn], 0, 0, 0);

  float bv[4];
#pragma unroll
  for (int jn = 0; jn < 4; jn++) bv[jn] = bias[wq * 64 + jn * 16 + c15];

#pragma unroll
  for (int mt = 0; mt < 4; mt++) {
#pragma unroll
    for (int rg = 0; rg < 4; rg++) {
      int row = m0 + mt * 16 + q * 4 + rg;
      int b = row / 400;
      int p = row - b * 400;
      u16* ob = g_x1b + (size_t)b * 102400 + p * 256;
#pragma unroll
      for (int jn = 0; jn < 4; jn++) {
        int col = wq * 64 + jn * 16 + c15;
        ob[col] = f2bf(fmaxf(acc[mt][jn][rg] + bv[jn], 0.f));
      }
    }
  }
}

// ---- pc conv: R28 structure, BK=128 as two 64-k halves, 18 stages ---------
__global__ __launch_bounds__(512) void pc_mfma_k() {
  __shared__ u16 As[3 * 8192];  // 3 bufs x (2 halves x 4096 u16) = 48 KB
  int t = threadIdx.x;
  int m0 = blockIdx.x * 64;
  int ks0 = blockIdx.y * KSLICE;
  u16* outp = g_y2p + (size_t)blockIdx.y * PS;

  int w = t >> 6, l = t & 63, quad = l >> 4, c15 = l & 15;

  // A staging (per half, identical to R25): thread t fills physical chunk
  // (t&7) of row (t>>3); content = logical chunk (t&7)^(row&7).
  int sr = t >> 3;
  int sc = t & 7;
  int cch = sc ^ (sr & 7);
  int fixed0;
  {
    int m = m0 + sr;
    int bb = m / 36;
    int s = m - bb * 36;
    int oy = s / 6;
    int ox = s - oy * 6;
    fixed0 = bb * 102400 + oy * 10240 + ox * 512 + cch * 8;
  }

  // B fragments: wave w owns cols [w*32, w*32+32) -> n16 = w*2+jn
  int bofs[2];
#pragma unroll
  for (int jn = 0; jn < 2; jn++) bofs[jn] = ((w * 2 + jn) << 9) + l * 8;

  f32x4 acc[4][2];
#pragma unroll
  for (int i = 0; i < 4; i++)
#pragma unroll
    for (int j = 0; j < 2; j++) acc[i][j] = (f32x4){0.f, 0.f, 0.f, 0.f};

  bf16x8 bpf[4][2];

  // issue stage st's A loads: 2 global_load_lds per wave (one per 64-k half).
  // 128-k window never crosses a kp boundary (k0 mult of 128, 128|256).
  auto STAGE = [&](int st, int buf) {
    int k0 = ks0 + st * 128;
    int kp = k0 >> 8, ic0 = k0 & 255;    // ic0 in {0,128}
    int ky = kp / 9, kx = kp - ky * 9;
    int off = ky * 5120 + kx * 256 + ic0;
    u16* l0 = &As[buf * 8192 + w * 512];          // half 0, wave-uniform base
    u16* l1 = &As[buf * 8192 + 4096 + w * 512];   // half 1
    __builtin_amdgcn_global_load_lds(
        (const __attribute__((address_space(1))) unsigned*)(g_x1b + fixed0 + off),
        (__attribute__((address_space(3))) unsigned*)l0, 16, 0, 0);
    __builtin_amdgcn_global_load_lds(
        (const __attribute__((address_space(1))) unsigned*)(g_x1b + fixed0 + off + 64),
        (__attribute__((address_space(3))) unsigned*)l1, 16, 0, 0);
  };
  // B prefetch for stage st (8 x 16B loads, L2-resident)
  auto BPF = [&](int st) {
    const u16* bp = g_wbF + ((size_t)((ks0 + st * 128) >> 5) << 13);
#pragma unroll
    for (int kc = 0; kc < 4; kc++)
#pragma unroll
      for (int jn = 0; jn < 2; jn++)
        bpf[kc][jn] = *(const bf16x8*)(bp + (kc << 13) + bofs[jn]);
  };
  // 32 MFMA, 16 ds_read_b128 on compile-time buffer index
  auto COMPUTE = [&](int buf) {
#pragma unroll
    for (int h = 0; h < 2; h++) {
#pragma unroll
      for (int kk = 0; kk < 2; kk++) {
#pragma unroll
        for (int i = 0; i < 4; i++) {
          int rr = i * 16 + c15;
          int pch = (kk * 4 + quad) ^ (rr & 7);
          bf16x8 af = *(const bf16x8*)&As[buf * 8192 + h * 4096 + rr * 64 + pch * 8];
#pragma unroll
          for (int jn = 0; jn < 2; jn++)
            acc[i][jn] = __builtin_amdgcn_mfma_f32_16x16x32_bf16(af, bpf[h * 2 + kk][jn], acc[i][jn], 0, 0, 0);
        }
      }
    }
  };

  // prologue: A0, B0, A1 (issue order pinned; A(st) is always oldest)
  STAGE(0, 0);
  asm volatile("" ::: "memory");
  BPF(0);
  asm volatile("" ::: "memory");
  STAGE(1, 1);
  asm volatile("" ::: "memory");

  // main loop: stages 0..14 (5 groups of 3); buffers compile-time via unroll.
  // Window at stage top: A(st)[2] + B(st)[8] + A(st+1)[2] = 12 -> vmcnt(10)
  // retires A(st).
  for (int mst = 0; mst < NSTG2 - 3; mst += 3) {
#pragma unroll
    for (int sub = 0; sub < 3; sub++) {
      int st = mst + sub;
      asm volatile("s_waitcnt vmcnt(10)" ::: "memory");
      __builtin_amdgcn_sched_barrier(0);
      __builtin_amdgcn_s_barrier();   // all A(st) visible; compute(st-1) done
      asm volatile("" ::: "memory");
      STAGE(st + 2, (sub + 2) % 3);   // overwrites buffer read at st-1: safe
      asm volatile("" ::: "memory");
      __builtin_amdgcn_s_setprio(1);
      COMPUTE(sub);                   // buf = st%3 = sub
      __builtin_amdgcn_s_setprio(0);
      BPF(st + 1);
      asm volatile("" ::: "memory");
    }
  }
  // tail: st = 15 (buf 0), 16 (buf 1), 17 (buf 2)
  asm volatile("s_waitcnt vmcnt(10)" ::: "memory");
  __builtin_amdgcn_sched_barrier(0);
  __builtin_amdgcn_s_barrier();
  asm volatile("" ::: "memory");
  STAGE(17, 2);
  asm volatile("" ::: "memory");
  __builtin_amdgcn_s_setprio(1);
  COMPUTE(0);
  __builtin_amdgcn_s_setprio(0);
  BPF(16);
  asm volatile("" ::: "memory");

  asm volatile("s_waitcnt vmcnt(10)" ::: "memory");
  __builtin_amdgcn_sched_barrier(0);
  __builtin_amdgcn_s_barrier();
  asm volatile("" ::: "memory");
  __builtin_amdgcn_s_setprio(1);
  COMPUTE(1);
  __builtin_amdgcn_s_setprio(0);
  BPF(17);
  asm volatile("" ::: "memory");

  asm volatile("s_waitcnt vmcnt(8)" ::: "memory");
  __builtin_amdgcn_sched_barrier(0);
  __builtin_amdgcn_s_barrier();
  asm volatile("" ::: "memory");
  __builtin_amdgcn_s_setprio(1);
  COMPUTE(2);
  __builtin_amdgcn_s_setprio(0);

  // epilogue: C/D map col=lane&15, row=quad*4+reg; wave w -> cols w*32..w*32+31
#pragma unroll
  for (int i = 0; i < 4; i++)
#pragma unroll
    for (int jn = 0; jn < 2; jn++) {
      int col = w * 32 + jn * 16 + c15;
#pragma unroll
      for (int rg = 0; rg < 4; rg++) {
        int row = m0 + i * 16 + quad * 4 + rg;
        outp[(size_t)row * 256 + col] = f2bf(acc[i][jn][rg]);
      }
    }
}

// ---------------- squash primary capsules (coalesced row-wise) -------------
__global__ __launch_bounds__(256) void squash_u_k(const float* __restrict__ pcb) {
  __shared__ float xs[256];
  __shared__ float scs[32];
  int m = blockIdx.x;          // 0..9215
  int t = threadIdx.x;
  int b = m / 36;
  int s = m - b * 36;
  float x = pcb[t];
  const u16* base = g_y2p + (size_t)m * 256 + t;
#pragma unroll
  for (int q = 0; q < KSPLIT; q++) x += bf2f(base[(size_t)q * PS]);
  xs[t] = x;
  __syncthreads();
  if (t < 32) {
    float sq = 0.f;
#pragma unroll
    for (int p = 0; p < 8; p++) {
      float v = xs[t + p * 32];
      sq = fmaf(v, v, sq);
    }
    scs[t] = (sq / (1.f + sq)) * rsqrtf(sq + 1e-7f);
  }
  __syncthreads();
  int g = t & 31, p = t >> 5;
  g_u[((size_t)b * 1152 + g * 36 + s) * 8 + p] = x * scs[g];
}

// ---------------- WU einsum (bf16 output) ----------------
__global__ __launch_bounds__(256) void wu_k(const float* __restrict__ W) {
  __shared__ float W_s[8][161];
  __shared__ float u_s[32][8];
  int n = blockIdx.x;
  int b0 = blockIdx.y * 32;
  int t = threadIdx.x;
  const float* Wn = W + (size_t)n * 1280;
  for (int i = t; i < 1280; i += 256) {
    int cd = i >> 3, p = i & 7;
    W_s[p][cd] = Wn[i];
  }
  {
    int bl = t >> 3, p = t & 7;
    u_s[bl][p] = g_u[(size_t)(b0 + bl) * 9216 + n * 8 + p];
  }
  __syncthreads();
#pragma unroll
  for (int i = 0; i < 20; i++) {
    int idx = t + 256 * i;
    int bl = idx / 160;
    int cd = idx - bl * 160;
    float acc = 0.f;
#pragma unroll
    for (int p = 0; p < 8; p++) acc = fmaf(u_s[bl][p], W_s[p][cd], acc);
    g_WU[((size_t)(b0 + bl) * 1152 + n) * 160 + cd] = f2bf(acc);
  }
}

// ---- fused routing: one block per b; iterations 0,1,2 with LDS reduce -----
// 512 threads = 32 groups x 16 lanes (lane = class, 10 active); 36 n/group.
__global__ __launch_bounds__(512) void route_all_k() {
  __shared__ float red_s[32 * 272];   // [grp][lane*17 + d], 34.8 KB
  __shared__ float vs[160];           // reduced ssum staging
  int b = blockIdx.x;
  int t = threadIdx.x;
  int lane = t & 15;
  int grp = t >> 4;            // 0..31
  bool active = lane < 10;
  int cl = active ? lane : 9;  // clamped for in-bounds loads

  const u16* wubase = g_WU + (size_t)b * 1152 * 160 + cl * 16;

  float v0r[16], v1r[16], acc[16];

  // REDUCE: sum 32 group-partials of acc into vs[160] (t<160 lanes do sums).
  auto REDUCE = [&]() {
#pragma unroll
    for (int d = 0; d < 16; d++) red_s[grp * 272 + lane * 17 + d] = acc[d];
    __syncthreads();
    if (t < 160) {
      int c = t >> 4, d = t & 15;
      float tot = 0.f;
#pragma unroll
      for (int g = 0; g < 32; g++) tot += red_s[g * 272 + c * 17 + d];
      vs[t] = tot;
    }
    __syncthreads();
  };
  // SQUASH vs[cl*16..] -> vr registers
  auto SQUASH = [&](float* vr) {
    float sq = 0.f;
#pragma unroll
    for (int d = 0; d < 16; d++) {
      vr[d] = vs[cl * 16 + d];
      sq = fmaf(vr[d], vr[d], sq);
    }
    float scale = (sq / (1.f + sq)) * rsqrtf(sq + 1e-7f);
#pragma unroll
    for (int d = 0; d < 16; d++) vr[d] *= scale;
  };

  // ---------------- iteration 0: c = softmax(0) = 0.1 exactly --------------
#pragma unroll
  for (int d = 0; d < 16; d++) acc[d] = 0.f;
  for (int i = 0; i < 36; i++) {
    const u16* row = wubase + (size_t)(grp * 36 + i) * 160;
    bf16x8 wlo = *(const bf16x8*)row;
    bf16x8 whi = *(const bf16x8*)(row + 8);
#pragma unroll
    for (int e = 0; e < 8; e++) {
      acc[e] += bf2f((u16)wlo[e]);
      acc[8 + e] += bf2f((u16)whi[e]);
    }
  }
#pragma unroll
  for (int d = 0; d < 16; d++) acc[d] *= 0.1f;
  REDUCE();
  SQUASH(v0r);

  // ---------------- iteration 1 -------------------------------------------
#pragma unroll
  for (int d = 0; d < 16; d++) acc[d] = 0.f;
  for (int i = 0; i < 36; i++) {
    const u16* row = wubase + (size_t)(grp * 36 + i) * 160;
    bf16x8 wlo = *(const bf16x8*)row;
    bf16x8 whi = *(const bf16x8*)(row + 8);
    float wu[16];
#pragma unroll
    for (int e = 0; e < 8; e++) {
      wu[e] = bf2f((u16)wlo[e]);
      wu[8 + e] = bf2f((u16)whi[e]);
    }
    float s0 = 0.f, s1 = 0.f;
#pragma unroll
    for (int d = 0; d < 8; d++) {
      s0 = fmaf(v0r[d], wu[d], s0);
      s1 = fmaf(v0r[8 + d], wu[8 + d], s1);
    }
    float bij = active ? 0.1f * (s0 + s1) : -3.0e38f;
    float mx = bij;
    mx = fmaxf(mx, __shfl_xor(mx, 1));
    mx = fmaxf(mx, __shfl_xor(mx, 2));
    mx = fmaxf(mx, __shfl_xor(mx, 4));
    mx = fmaxf(mx, __shfl_xor(mx, 8));
    float e = __expf(bij - mx);
    float es = e;
    es += __shfl_xor(es, 1);
    es += __shfl_xor(es, 2);
    es += __shfl_xor(es, 4);
    es += __shfl_xor(es, 8);
    float sm = e / es;
#pragma unroll
    for (int d = 0; d < 16; d++) acc[d] = fmaf(sm, wu[d], acc[d]);
  }
  REDUCE();
  SQUASH(v1r);

  // ---------------- iteration 2 -------------------------------------------
#pragma unroll
  for (int d = 0; d < 16; d++) acc[d] = 0.f;
  for (int i = 0; i < 36; i++) {
    const u16* row = wubase + (size_t)(grp * 36 + i) * 160;
    bf16x8 wlo = *(const bf16x8*)row;
    bf16x8 whi = *(const bf16x8*)(row + 8);
    float wu[16];
#pragma unroll
    for (int e = 0; e < 8; e++) {
      wu[e] = bf2f((u16)wlo[e]);
      wu[8 + e] = bf2f((u16)whi[e]);
    }
    // bij1 = 0.1 * dot(v0, wu); sm1 = softmax(bij1)
    float s0 = 0.f, s1 = 0.f;
#pragma unroll
    for (int d = 0; d < 8; d++) {
      s0 = fmaf(v0r[d], wu[d], s0);
      s1 = fmaf(v0r[8 + d], wu[8 + d], s1);
    }
    float bij = active ? 0.1f * (s0 + s1) : -3.0e38f;
    float mx = bij;
    mx = fmaxf(mx, __shfl_xor(mx, 1));
    mx = fmaxf(mx, __shfl_xor(mx, 2));
    mx = fmaxf(mx, __shfl_xor(mx, 4));
    mx = fmaxf(mx, __shfl_xor(mx, 8));
    float e = __expf(bij - mx);
    float es = e;
    es += __shfl_xor(es, 1);
    es += __shfl_xor(es, 2);
    es += __shfl_xor(es, 4);
    es += __shfl_xor(es, 8);
    float sm = e / es;
    // bij2 = bij1 + sm1 * dot(v1, wu); sm2 = softmax(bij2)
    float q0 = 0.f, q1 = 0.f;
#pragma unroll
    for (int d = 0; d < 8; d++) {
      q0 = fmaf(v1r[d], wu[d], q0);
      q1 = fmaf(v1r[8 + d], wu[8 + d], q1);
    }
    bij = active ? (bij + sm * (q0 + q1)) : -3.0e38f;
    float mx2 = bij;
    mx2 = fmaxf(mx2, __shfl_xor(mx2, 1));
    mx2 = fmaxf(mx2, __shfl_xor(mx2, 2));
    mx2 = fmaxf(mx2, __shfl_xor(mx2, 4));
    mx2 = fmaxf(mx2, __shfl_xor(mx2, 8));
    float e2 = __expf(bij - mx2);
    float es2 = e2;
    es2 += __shfl_xor(es2, 1);
    es2 += __shfl_xor(es2, 2);
    es2 += __shfl_xor(es2, 4);
    es2 += __shfl_xor(es2, 8);
    sm = e2 / es2;
#pragma unroll
    for (int d = 0; d < 16; d++) acc[d] = fmaf(sm, wu[d], acc[d]);
  }
  // final reduce -> write ssum slot 2 (plain coalesced stores; no atomics)
#pragma unroll
  for (int d = 0; d < 16; d++) red_s[grp * 272 + lane * 17 + d] = acc[d];
  __syncthreads();
  if (t < 160) {
    int c = t >> 4, d = t & 15;
    float tot = 0.f;
#pragma unroll
    for (int g = 0; g < 32; g++) tot += red_s[g * 272 + c * 17 + d];
    g_ssum[2 * 40960 + b * 160 + t] = tot;
  }
}

// ---------------- decoder (dec1 computes v[lab] + clf inline) --------------
__global__ __launch_bounds__(256) void dec1_k(const int* __restrict__ labels,
                                              const float* __restrict__ w1,
                                              const float* __restrict__ b1,
                                              float* __restrict__ out) {
  int b = blockIdx.y;
  int j = blockIdx.x * 256 + threadIdx.x;
  int lab = labels[b];
  // v[b][lab] from ssum slot 2 (squash inline; broadcast loads)
  const float* s = g_ssum + 2 * 40960 + b * 160 + lab * 16;
  float vv[16];
  float sq = 0.f;
#pragma unroll
  for (int d = 0; d < 16; d++) { vv[d] = s[d]; sq = fmaf(s[d], s[d], sq); }
  float scale = (sq / (1.f + sq)) * rsqrtf(sq + 1e-7f);
  float acc = b1[j];
#pragma unroll
  for (int d = 0; d < 16; d++)
    acc = fmaf(vv[d] * scale, w1[(size_t)(lab * 16 + d) * 512 + j], acc);
  g_h1[b * 512 + j] = fmaxf(acc, 0.f);

  // clf: block x==0, threads 0..9 write out[b*10+c]
  if (blockIdx.x == 0 && threadIdx.x < 10) {
    int c = threadIdx.x;
    const float* sc = g_ssum + 2 * 40960 + b * 160 + c * 16;
    float sqc = 0.f;
#pragma unroll
    for (int d = 0; d < 16; d++) sqc = fmaf(sc[d], sc[d], sqc);
    float scc = (sqc / (1.f + sqc)) * rsqrtf(sqc + 1e-7f);
    out[b * 10 + c] = scc * sqrtf(sqc);
  }
}

// dec2: 2 batches per block — w2 stream reused 2x. Grid (4, 128).
__global__ __launch_bounds__(256) void dec2_k(const float* __restrict__ w2,
                                              const float* __restrict__ b2) {
  __shared__ float h_s[2][512];
  int b0 = blockIdx.y * 2;
  int j = blockIdx.x * 256 + threadIdx.x;
  int t = threadIdx.x;
  for (int i = t; i < 1024; i += 256) h_s[i >> 9][i & 511] = g_h1[b0 * 512 + i];
  __syncthreads();
  float a0 = b2[j], a1 = a0;
#pragma unroll 8
  for (int k = 0; k < 512; k++) {
    float wv = w2[(size_t)k * 1024 + j];
    a0 = fmaf(h_s[0][k], wv, a0);
    a1 = fmaf(h_s[1][k], wv, a1);
  }
  g_h2[b0 * 1024 + j] = fmaxf(a0, 0.f);
  g_h2[(b0 + 1) * 1024 + j] = fmaxf(a1, 0.f);
}

// dec3: 2 batches per block — w3 stream reused 2x. Grid (4, 128).
__global__ __launch_bounds__(256) void dec3_k(const float* __restrict__ w3,
                                              const float* __restrict__ b3,
                                              float* __restrict__ out) {
  __shared__ float h_s[2][1024];
  int b0 = blockIdx.y * 2;
  int t = threadIdx.x;
  for (int i = t; i < 2048; i += 256) h_s[i >> 10][i & 1023] = g_h2[b0 * 1024 + i];
  __syncthreads();
  if (t >= 196) return;
  int j = blockIdx.x * 196 + t;
  float a0 = b3[j], a1 = a0;
#pragma unroll 8
  for (int k = 0; k < 1024; k++) {
    float wv = w3[(size_t)k * 784 + j];
    a0 = fmaf(h_s[0][k], wv, a0);
    a1 = fmaf(h_s[1][k], wv, a1);
  }
  out[2560 + b0 * 784 + j] = 1.f / (1.f + __expf(-a0));
  out[2560 + (b0 + 1) * 784 + j] = 1.f / (1.f + __expf(-a1));
}

// ---------------------------------------------------------------------------
extern "C" void kernel_launch(void* const* d_in, const int* in_sizes, int n_in,
                              void* d_out, int out_size, void* d_ws,
                              size_t ws_size, hipStream_t stream) {
  const float* inputs = (const float*)d_in[0];
  const int* labels = (const int*)d_in[1];
  const float* conv1_w = (const float*)d_in[2];
  const float* conv1_b = (const float*)d_in[3];
  const float* pc_w = (const float*)d_in[4];
  const float* pc_b = (const float*)d_in[5];
  const float* rw = (const float*)d_in[6];
  const float* dw1 = (const float*)d_in[7];
  const float* db1 = (const float*)d_in[8];
  const float* dw2 = (const float*)d_in[9];
  const float* db2 = (const float*)d_in[10];
  const float* dw3 = (const float*)d_in[11];
  const float* db3 = (const float*)d_in[12];
  float* out = (float*)d_out;
  (void)d_ws; (void)ws_size; (void)in_sizes; (void)n_in;

  wconv_k<<<dim3(16, 32), 256, 0, stream>>>(pc_w);
  wb1_k<<<96, 256, 0, stream>>>(conv1_w);
  im2col_k<<<dim3(256, 2), 256, 0, stream>>>(inputs);
  conv1_mfma_k<<<1600, 256, 0, stream>>>(conv1_b);
  pc_mfma_k<<<dim3(144, KSPLIT), 512, 0, stream>>>();
  squash_u_k<<<9216, 256, 0, stream>>>(pc_b);
  wu_k<<<dim3(1152, 8), 256, 0, stream>>>(rw);
  route_all_k<<<256, 512, 0, stream>>>();
  dec1_k<<<dim3(2, 256), 256, 0, stream>>>(labels, dw1, db1, out);
  dec2_k<<<dim3(4, 128), 256, 0, stream>>>(dw2, db2);
  dec3_k<<<dim3(4, 128), 256, 0, stream>>>(dw3, db3, out);
}

// Round 15
// 474.634 us; speedup vs baseline: 1.0278x; 1.0278x over previous
//
#include <hip/hip_runtime.h>
#include <math.h>

// ---------------------------------------------------------------------------
// CapsuleNet forward. R34: revert routing to R32's split form (best-measured
// 482.0us; R33's fused route_all was 487.8 — serialized WU passes lost the
// inter-kernel overlap of back-to-back launches). One new tweak: g_u stored
// as bf16 (g_ub) — squash_u write + wu read round-trip drops 37.7MB fp32 ->
// 18.9MB bf16 (~6-10us at HBM ceiling). wu_k loads u rows as bf16x8 vectors.
// u is |u|<1 and already feeds bf16 WU, so one more bf16 rounding is ~0.4%
// relative (absmax headroom 0.02 vs current 0.0039).
// pc_mfma_k frozen at R28 best. Everything else identical to R32.
// ---------------------------------------------------------------------------

typedef unsigned short u16;
typedef short bf16x8 __attribute__((ext_vector_type(8)));
typedef float f32x4 __attribute__((ext_vector_type(4)));

#define PS 2359296   // 9216*256, one y2 partial buffer
#define KSPLIT 9
#define KSLICE 2304  // 20736/9
#define NSTG2 18     // 2304/128

__device__ u16 g_x1b[256 * 400 * 256];          // conv1 out NHWC bf16 (52 MB)
__device__ u16 g_wbF[648 * 16 * 512];           // pc_w bf16, MFMA frag order (10.6 MB)
__device__ u16 g_y2p[(size_t)KSPLIT * PS];      // pc GEMM K-partials bf16 (42.5 MB)
__device__ u16 g_ub[256 * 1152 * 8];            // squashed primary caps bf16 (18.9 MB)
__device__ u16 g_WU[(size_t)256 * 1152 * 160];  // u_hat bf16 (94.4 MB)
__device__ float g_ssum[3 * 256 * 160];
__device__ float g_h1[256 * 512];
__device__ float g_h2[256 * 1024];

// conv1-as-GEMM buffers
__device__ __attribute__((aligned(256))) u16 g_im2[(size_t)102400 * 104];  // im2col bf16, 104-padded rows (21.3 MB)
__device__ __attribute__((aligned(256))) u16 g_wb1[48 * 512];              // conv1_w frags (48 KB)

__device__ __forceinline__ u16 f2bf(float f) {
  union { float f; unsigned u; } v; v.f = f;
  unsigned r = (v.u + 0x7FFFu + ((v.u >> 16) & 1u)) >> 16;  // RNE
  return (u16)r;
}
__device__ __forceinline__ float bf2f(u16 h) {
  union { unsigned u; float f; } v; v.u = ((unsigned)h) << 16;
  return v.f;
}

// ---------------- zero the atomic accumulators ----------------
__global__ __launch_bounds__(256) void zero_ssum_k() {
  int i = blockIdx.x * 256 + threadIdx.x;
  if (i < 3 * 256 * 160) g_ssum[i] = 0.f;
}

// ------ pc_w fp32 [oc][ic][kp] -> bf16 16x16 fragment order (R25) ---------
__global__ __launch_bounds__(256) void wconv_k(const float* __restrict__ w) {
  __shared__ float Ws[16 * 648];   // [ocl][ic_local*81 + kp] 41.5 KB
  int n16 = blockIdx.x;   // 0..15
  int icb = blockIdx.y;   // 0..31
  int c = icb >> 2, h = icb & 3;
  int t = threadIdx.x;
#pragma unroll
  for (int ocl = 0; ocl < 16; ocl++) {
    const float* src = w + (size_t)(n16 * 16 + ocl) * 20736 + icb * 648;
    for (int i = t; i < 648; i += 256) Ws[ocl * 648 + i] = src[i];
  }
  __syncthreads();
  for (int wi = t; wi < 81 * 128; wi += 256) {
    int kp = wi >> 7;
    int r7 = wi & 127;
    int llh = r7 >> 3, j = wi & 7;
    g_wbF[(((size_t)kp * 8 + c) * 16 + n16) * 512 + h * 128 + r7] =
        f2bf(Ws[llh * 648 + j * 81 + kp]);
  }
}

// ------ conv1_w fp32 [oc][81] -> bf16 MFMA B-fragment order ----------------
__global__ __launch_bounds__(256) void wb1_k(const float* __restrict__ w) {
  int idx = blockIdx.x * 256 + threadIdx.x;   // 0..24575
  int frag = idx >> 9;     // kc*16 + n16
  int r = idx & 511;
  int ll = r >> 3, j = r & 7;
  int kc = frag >> 4, n16 = frag & 15;
  int k = kc * 32 + ((ll >> 4) << 3) + j;
  int oc = n16 * 16 + (ll & 15);
  float v = (k < 81) ? w[oc * 81 + k] : 0.f;
  g_wb1[idx] = f2bf(v);
}

// ------ im2col: input fp32 [b][28][28] -> bf16 patches [m][104] ------------
__global__ __launch_bounds__(256) void im2col_k(const float* __restrict__ in) {
  __shared__ u16 im_s[784];
  int b = blockIdx.x;
  int t = threadIdx.x;
  for (int i = t; i < 784; i += 256) im_s[i] = f2bf(in[b * 784 + i]);
  __syncthreads();
  u16* outp = g_im2 + (size_t)b * 41600;   // 400*104
  int base = blockIdx.y * 2600;            // octet halves (5200 octets/image)
  for (int ii = t; ii < 2600; ii += 256) {
    int idx = base + ii;
    int p = idx / 13;                      // pixel 0..399
    int ko = (idx - p * 13) * 8;           // 0,8,...,96
    int oy = p / 20, ox = p - oy * 20;
    bf16x8 v;
#pragma unroll
    for (int e = 0; e < 8; e++) {
      int k = ko + e;
      u16 x = 0;
      if (k < 81) {
        int ky = k / 9, kx = k - ky * 9;
        x = im_s[(oy + ky) * 28 + ox + kx];
      }
      v[e] = (short)x;
    }
    *(bf16x8*)(outp + (size_t)p * 104 + ko) = v;   // 16B aligned (208B rows)
  }
}

// ------ conv1 as MFMA GEMM: M=102400, N=256, K=96 --------------------------
__global__ __launch_bounds__(256) void conv1_mfma_k(const float* __restrict__ bias) {
  int t = threadIdx.x;
  int wq = t >> 6;          // wave's oc-quarter
  int l = t & 63;
  int q = l >> 4, c15 = l & 15;
  int m0 = blockIdx.x * 64;

  // B fragments: 3 kc x 4 n16 (this wave's quarter)
  bf16x8 bf[3][4];
#pragma unroll
  for (int kc = 0; kc < 3; kc++)
#pragma unroll
    for (int jn = 0; jn < 4; jn++)
      bf[kc][jn] = *(const bf16x8*)&g_wb1[((kc * 16 + wq * 4 + jn) << 9) + l * 8];

  // A fragments: 4 m-tiles x 3 kc
  bf16x8 af[4][3];
#pragma unroll
  for (int mt = 0; mt < 4; mt++) {
    const u16* ap = g_im2 + (size_t)(m0 + mt * 16 + c15) * 104 + q * 8;
#pragma unroll
    for (int kc = 0; kc < 3; kc++)
      af[mt][kc] = *(const bf16x8*)(ap + kc * 32);
  }

  f32x4 acc[4][4];
#pragma unroll
  for (int mt = 0; mt < 4; mt++)
#pragma unroll
    for (int jn = 0; jn < 4; jn++) acc[mt][jn] = (f32x4){0.f, 0.f, 0.f, 0.f};

#pragma unroll
  for (int kc = 0; kc < 3; kc++)
#pragma unroll
    for (int mt = 0; mt < 4; mt++)
#pragma unroll
      for (int jn = 0; jn < 4; jn++)
        acc[mt][jn] = __builtin_amdgcn_mfma_f32_16x16x32_bf16(af[mt][kc], bf[kc][jn], acc[mt][jn], 0, 0, 0);

  float bv[4];
#pragma unroll
  for (int jn = 0; jn < 4; jn++) bv[jn] = bias[wq * 64 + jn * 16 + c15];

#pragma unroll
  for (int mt = 0; mt < 4; mt++) {
#pragma unroll
    for (int rg = 0; rg < 4; rg++) {
      int row = m0 + mt * 16 + q * 4 + rg;
      int b = row / 400;
      int p = row - b * 400;
      u16* ob = g_x1b + (size_t)b * 102400 + p * 256;
#pragma unroll
      for (int jn = 0; jn < 4; jn++) {
        int col = wq * 64 + jn * 16 + c15;
        ob[col] = f2bf(fmaxf(acc[mt][jn][rg] + bv[jn], 0.f));
      }
    }
  }
}

// ---- pc conv: R28 structure, BK=128 as two 64-k halves, 18 stages ---------
__global__ __launch_bounds__(512) void pc_mfma_k() {
  __shared__ u16 As[3 * 8192];  // 3 bufs x (2 halves x 4096 u16) = 48 KB
  int t = threadIdx.x;
  int m0 = blockIdx.x * 64;
  int ks0 = blockIdx.y * KSLICE;
  u16* outp = g_y2p + (size_t)blockIdx.y * PS;

  int w = t >> 6, l = t & 63, quad = l >> 4, c15 = l & 15;

  // A staging (per half, identical to R25): thread t fills physical chunk
  // (t&7) of row (t>>3); content = logical chunk (t&7)^(row&7).
  int sr = t >> 3;
  int sc = t & 7;
  int cch = sc ^ (sr & 7);
  int fixed0;
  {
    int m = m0 + sr;
    int bb = m / 36;
    int s = m - bb * 36;
    int oy = s / 6;
    int ox = s - oy * 6;
    fixed0 = bb * 102400 + oy * 10240 + ox * 512 + cch * 8;
  }

  // B fragments: wave w owns cols [w*32, w*32+32) -> n16 = w*2+jn
  int bofs[2];
#pragma unroll
  for (int jn = 0; jn < 2; jn++) bofs[jn] = ((w * 2 + jn) << 9) + l * 8;

  f32x4 acc[4][2];
#pragma unroll
  for (int i = 0; i < 4; i++)
#pragma unroll
    for (int j = 0; j < 2; j++) acc[i][j] = (f32x4){0.f, 0.f, 0.f, 0.f};

  bf16x8 bpf[4][2];

  // issue stage st's A loads: 2 global_load_lds per wave (one per 64-k half).
  // 128-k window never crosses a kp boundary (k0 mult of 128, 128|256).
  auto STAGE = [&](int st, int buf) {
    int k0 = ks0 + st * 128;
    int kp = k0 >> 8, ic0 = k0 & 255;    // ic0 in {0,128}
    int ky = kp / 9, kx = kp - ky * 9;
    int off = ky * 5120 + kx * 256 + ic0;
    u16* l0 = &As[buf * 8192 + w * 512];          // half 0, wave-uniform base
    u16* l1 = &As[buf * 8192 + 4096 + w * 512];   // half 1
    __builtin_amdgcn_global_load_lds(
        (const __attribute__((address_space(1))) unsigned*)(g_x1b + fixed0 + off),
        (__attribute__((address_space(3))) unsigned*)l0, 16, 0, 0);
    __builtin_amdgcn_global_load_lds(
        (const __attribute__((address_space(1))) unsigned*)(g_x1b + fixed0 + off + 64),
        (__attribute__((address_space(3))) unsigned*)l1, 16, 0, 0);
  };
  // B prefetch for stage st (8 x 16B loads, L2-resident)
  auto BPF = [&](int st) {
    const u16* bp = g_wbF + ((size_t)((ks0 + st * 128) >> 5) << 13);
#pragma unroll
    for (int kc = 0; kc < 4; kc++)
#pragma unroll
      for (int jn = 0; jn < 2; jn++)
        bpf[kc][jn] = *(const bf16x8*)(bp + (kc << 13) + bofs[jn]);
  };
  // 32 MFMA, 16 ds_read_b128 on compile-time buffer index
  auto COMPUTE = [&](int buf) {
#pragma unroll
    for (int h = 0; h < 2; h++) {
#pragma unroll
      for (int kk = 0; kk < 2; kk++) {
#pragma unroll
        for (int i = 0; i < 4; i++) {
          int rr = i * 16 + c15;
          int pch = (kk * 4 + quad) ^ (rr & 7);
          bf16x8 af = *(const bf16x8*)&As[buf * 8192 + h * 4096 + rr * 64 + pch * 8];
#pragma unroll
          for (int jn = 0; jn < 2; jn++)
            acc[i][jn] = __builtin_amdgcn_mfma_f32_16x16x32_bf16(af, bpf[h * 2 + kk][jn], acc[i][jn], 0, 0, 0);
        }
      }
    }
  };

  // prologue: A0, B0, A1 (issue order pinned; A(st) is always oldest)
  STAGE(0, 0);
  asm volatile("" ::: "memory");
  BPF(0);
  asm volatile("" ::: "memory");
  STAGE(1, 1);
  asm volatile("" ::: "memory");

  // main loop: stages 0..14 (5 groups of 3); buffers compile-time via unroll.
  // Window at stage top: A(st)[2] + B(st)[8] + A(st+1)[2] = 12 -> vmcnt(10)
  // retires A(st).
  for (int mst = 0; mst < NSTG2 - 3; mst += 3) {
#pragma unroll
    for (int sub = 0; sub < 3; sub++) {
      int st = mst + sub;
      asm volatile("s_waitcnt vmcnt(10)" ::: "memory");
      __builtin_amdgcn_sched_barrier(0);
      __builtin_amdgcn_s_barrier();   // all A(st) visible; compute(st-1) done
      asm volatile("" ::: "memory");
      STAGE(st + 2, (sub + 2) % 3);   // overwrites buffer read at st-1: safe
      asm volatile("" ::: "memory");
      __builtin_amdgcn_s_setprio(1);
      COMPUTE(sub);                   // buf = st%3 = sub
      __builtin_amdgcn_s_setprio(0);
      BPF(st + 1);
      asm volatile("" ::: "memory");
    }
  }
  // tail: st = 15 (buf 0), 16 (buf 1), 17 (buf 2)
  asm volatile("s_waitcnt vmcnt(10)" ::: "memory");
  __builtin_amdgcn_sched_barrier(0);
  __builtin_amdgcn_s_barrier();
  asm volatile("" ::: "memory");
  STAGE(17, 2);
  asm volatile("" ::: "memory");
  __builtin_amdgcn_s_setprio(1);
  COMPUTE(0);
  __builtin_amdgcn_s_setprio(0);
  BPF(16);
  asm volatile("" ::: "memory");

  asm volatile("s_waitcnt vmcnt(10)" ::: "memory");
  __builtin_amdgcn_sched_barrier(0);
  __builtin_amdgcn_s_barrier();
  asm volatile("" ::: "memory");
  __builtin_amdgcn_s_setprio(1);
  COMPUTE(1);
  __builtin_amdgcn_s_setprio(0);
  BPF(17);
  asm volatile("" ::: "memory");

  asm volatile("s_waitcnt vmcnt(8)" ::: "memory");
  __builtin_amdgcn_sched_barrier(0);
  __builtin_amdgcn_s_barrier();
  asm volatile("" ::: "memory");
  __builtin_amdgcn_s_setprio(1);
  COMPUTE(2);
  __builtin_amdgcn_s_setprio(0);

  // epilogue: C/D map col=lane&15, row=quad*4+reg; wave w -> cols w*32..w*32+31
#pragma unroll
  for (int i = 0; i < 4; i++)
#pragma unroll
    for (int jn = 0; jn < 2; jn++) {
      int col = w * 32 + jn * 16 + c15;
#pragma unroll
      for (int rg = 0; rg < 4; rg++) {
        int row = m0 + i * 16 + quad * 4 + rg;
        outp[(size_t)row * 256 + col] = f2bf(acc[i][jn][rg]);
      }
    }
}

// ---------------- squash primary capsules (bf16 output) --------------------
__global__ __launch_bounds__(256) void squash_u_k(const float* __restrict__ pcb) {
  __shared__ float xs[256];
  __shared__ float scs[32];
  int m = blockIdx.x;          // 0..9215
  int t = threadIdx.x;
  int b = m / 36;
  int s = m - b * 36;
  float x = pcb[t];
  const u16* base = g_y2p + (size_t)m * 256 + t;
#pragma unroll
  for (int q = 0; q < KSPLIT; q++) x += bf2f(base[(size_t)q * PS]);
  xs[t] = x;
  __syncthreads();
  if (t < 32) {
    float sq = 0.f;
#pragma unroll
    for (int p = 0; p < 8; p++) {
      float v = xs[t + p * 32];
      sq = fmaf(v, v, sq);
    }
    scs[t] = (sq / (1.f + sq)) * rsqrtf(sq + 1e-7f);
  }
  __syncthreads();
  int g = t & 31, p = t >> 5;
  g_ub[((size_t)b * 1152 + g * 36 + s) * 8 + p] = f2bf(x * scs[g]);
}

// ---------------- WU einsum (bf16 u input, bf16 output) --------------------
__global__ __launch_bounds__(256) void wu_k(const float* __restrict__ W) {
  __shared__ float W_s[8][161];
  __shared__ float u_s[32][8];
  int n = blockIdx.x;
  int b0 = blockIdx.y * 32;
  int t = threadIdx.x;
  const float* Wn = W + (size_t)n * 1280;
  for (int i = t; i < 1280; i += 256) {
    int cd = i >> 3, p = i & 7;
    W_s[p][cd] = Wn[i];
  }
  if (t < 32) {
    bf16x8 uv = *(const bf16x8*)&g_ub[(size_t)(b0 + t) * 9216 + n * 8];
#pragma unroll
    for (int e = 0; e < 8; e++) u_s[t][e] = bf2f((u16)uv[e]);
  }
  __syncthreads();
#pragma unroll
  for (int i = 0; i < 20; i++) {
    int idx = t + 256 * i;
    int bl = idx / 160;
    int cd = idx - bl * 160;
    float acc = 0.f;
#pragma unroll
    for (int p = 0; p < 8; p++) acc = fmaf(u_s[bl][p], W_s[p][cd], acc);
    g_WU[((size_t)(b0 + bl) * 1152 + n) * 160 + cd] = f2bf(acc);
  }
}

// ---------------- iter0 reduction (bf16 input) ----------------
__global__ __launch_bounds__(256) void red0_k() {
  int b = blockIdx.x;
  int chunk = blockIdx.y;
  int t = threadIdx.x;
  if (t >= 160) return;
  const u16* base = g_WU + ((size_t)b * 1152 + chunk * 144) * 160 + t;
  float acc = 0.f;
  for (int n = 0; n < 144; n++) acc += bf2f(base[(size_t)n * 160]);
  atomicAdd(&g_ssum[b * 160 + t], 0.1f * acc);
}

// ---------------- routing iteration: lane = class, in-block squash ---------
template <int IT>
__global__ __launch_bounds__(256) void routing_iter_k() {
  __shared__ float red_s[16 * 272];   // [grp][lane*17 + d], 17-padded, 17.4 KB
  int b = blockIdx.x;
  int nb = blockIdx.y;
  int t = threadIdx.x;
  int lane = t & 15;           // class c (0..9 active)
  int grp = t >> 4;            // 0..15, each group handles 9 n's
  bool active = lane < 10;
  int cl = active ? lane : 9;  // clamped for safe (in-bounds) loads

  float v0r[16];
  {
    const float* s0 = g_ssum + b * 160 + cl * 16;
    float sq = 0.f;
#pragma unroll
    for (int d = 0; d < 16; d++) { v0r[d] = s0[d]; sq = fmaf(s0[d], s0[d], sq); }
    float scale = (sq / (1.f + sq)) * rsqrtf(sq + 1e-7f);
#pragma unroll
    for (int d = 0; d < 16; d++) v0r[d] *= scale;
  }
  float v1r[16];
  if (IT == 2) {
    const float* s1 = g_ssum + 40960 + b * 160 + cl * 16;
    float sq = 0.f;
#pragma unroll
    for (int d = 0; d < 16; d++) { v1r[d] = s1[d]; sq = fmaf(s1[d], s1[d], sq); }
    float scale = (sq / (1.f + sq)) * rsqrtf(sq + 1e-7f);
#pragma unroll
    for (int d = 0; d < 16; d++) v1r[d] *= scale;
  }

  float acc[16];
#pragma unroll
  for (int d = 0; d < 16; d++) acc[d] = 0.f;

  float* ssum_out = g_ssum + IT * 40960;

  for (int ni = 0; ni < 9; ni++) {
    int n = nb * 144 + grp * 9 + ni;
    const u16* row = g_WU + ((size_t)b * 1152 + n) * 160 + cl * 16;
    bf16x8 wlo = *(const bf16x8*)row;         // 32B-aligned
    bf16x8 whi = *(const bf16x8*)(row + 8);
    float wu[16];
#pragma unroll
    for (int e = 0; e < 8; e++) {
      wu[e] = bf2f((u16)wlo[e]);
      wu[8 + e] = bf2f((u16)whi[e]);
    }

    // bij = 0.1 * dot(v0[c], wu[c]) — serial in-thread, 2 partial chains
    float s0 = 0.f, s1 = 0.f;
#pragma unroll
    for (int d = 0; d < 8; d++) {
      s0 = fmaf(v0r[d], wu[d], s0);
      s1 = fmaf(v0r[8 + d], wu[8 + d], s1);
    }
    float bij = active ? 0.1f * (s0 + s1) : -3.0e38f;

    // softmax over classes (16-lane group; inactive lanes -> exp = 0)
    float mx = bij;
    mx = fmaxf(mx, __shfl_xor(mx, 1));
    mx = fmaxf(mx, __shfl_xor(mx, 2));
    mx = fmaxf(mx, __shfl_xor(mx, 4));
    mx = fmaxf(mx, __shfl_xor(mx, 8));
    float e = __expf(bij - mx);
    float es = e;
    es += __shfl_xor(es, 1);
    es += __shfl_xor(es, 2);
    es += __shfl_xor(es, 4);
    es += __shfl_xor(es, 8);
    float sm = e / es;

    if (IT == 2) {
      // agreement uses s_ij = c*WU: bij += sm * dot(v1[c], wu[c])
      float q0 = 0.f, q1 = 0.f;
#pragma unroll
      for (int d = 0; d < 8; d++) {
        q0 = fmaf(v1r[d], wu[d], q0);
        q1 = fmaf(v1r[8 + d], wu[8 + d], q1);
      }
      bij = active ? (bij + sm * (q0 + q1)) : -3.0e38f;
      float mx2 = bij;
      mx2 = fmaxf(mx2, __shfl_xor(mx2, 1));
      mx2 = fmaxf(mx2, __shfl_xor(mx2, 2));
      mx2 = fmaxf(mx2, __shfl_xor(mx2, 4));
      mx2 = fmaxf(mx2, __shfl_xor(mx2, 8));
      float e2 = __expf(bij - mx2);
      float es2 = e2;
      es2 += __shfl_xor(es2, 1);
      es2 += __shfl_xor(es2, 2);
      es2 += __shfl_xor(es2, 4);
      es2 += __shfl_xor(es2, 8);
      sm = e2 / es2;
    }

#pragma unroll
    for (int d = 0; d < 16; d++) acc[d] = fmaf(sm, wu[d], acc[d]);
  }

  // block-level reduction: 16 group-partials -> 1 coalesced atomic per output
#pragma unroll
  for (int d = 0; d < 16; d++) red_s[grp * 272 + lane * 17 + d] = acc[d];
  __syncthreads();
  if (t < 160) {
    int c = t >> 4, d = t & 15;
    float tot = 0.f;
#pragma unroll
    for (int g = 0; g < 16; g++) tot += red_s[g * 272 + c * 17 + d];
    atomicAdd(&ssum_out[b * 160 + t], tot);
  }
}

// ---------------- decoder (dec1 computes v[lab] + clf inline) --------------
__global__ __launch_bounds__(256) void dec1_k(const int* __restrict__ labels,
                                              const float* __restrict__ w1,
                                              const float* __restrict__ b1,
                                              float* __restrict__ out) {
  int b = blockIdx.y;
  int j = blockIdx.x * 256 + threadIdx.x;
  int lab = labels[b];
  // v[b][lab] from ssum slot 2 (squash inline; broadcast loads)
  const float* s = g_ssum + 2 * 40960 + b * 160 + lab * 16;
  float vv[16];
  float sq = 0.f;
#pragma unroll
  for (int d = 0; d < 16; d++) { vv[d] = s[d]; sq = fmaf(s[d], s[d], sq); }
  float scale = (sq / (1.f + sq)) * rsqrtf(sq + 1e-7f);
  float acc = b1[j];
#pragma unroll
  for (int d = 0; d < 16; d++)
    acc = fmaf(vv[d] * scale, w1[(size_t)(lab * 16 + d) * 512 + j], acc);
  g_h1[b * 512 + j] = fmaxf(acc, 0.f);

  // clf: block x==0, threads 0..9 write out[b*10+c]
  if (blockIdx.x == 0 && threadIdx.x < 10) {
    int c = threadIdx.x;
    const float* sc = g_ssum + 2 * 40960 + b * 160 + c * 16;
    float sqc = 0.f;
#pragma unroll
    for (int d = 0; d < 16; d++) sqc = fmaf(sc[d], sc[d], sqc);
    float scc = (sqc / (1.f + sqc)) * rsqrtf(sqc + 1e-7f);
    out[b * 10 + c] = scc * sqrtf(sqc);
  }
}

// dec2: 2 batches per block — w2 stream reused 2x. Grid (4, 128).
__global__ __launch_bounds__(256) void dec2_k(const float* __restrict__ w2,
                                              const float* __restrict__ b2) {
  __shared__ float h_s[2][512];
  int b0 = blockIdx.y * 2;
  int j = blockIdx.x * 256 + threadIdx.x;
  int t = threadIdx.x;
  for (int i = t; i < 1024; i += 256) h_s[i >> 9][i & 511] = g_h1[b0 * 512 + i];
  __syncthreads();
  float a0 = b2[j], a1 = a0;
#pragma unroll 8
  for (int k = 0; k < 512; k++) {
    float wv = w2[(size_t)k * 1024 + j];
    a0 = fmaf(h_s[0][k], wv, a0);
    a1 = fmaf(h_s[1][k], wv, a1);
  }
  g_h2[b0 * 1024 + j] = fmaxf(a0, 0.f);
  g_h2[(b0 + 1) * 1024 + j] = fmaxf(a1, 0.f);
}

// dec3: 2 batches per block — w3 stream reused 2x. Grid (4, 128).
__global__ __launch_bounds__(256) void dec3_k(const float* __restrict__ w3,
                                              const float* __restrict__ b3,
                                              float* __restrict__ out) {
  __shared__ float h_s[2][1024];
  int b0 = blockIdx.y * 2;
  int t = threadIdx.x;
  for (int i = t; i < 2048; i += 256) h_s[i >> 10][i & 1023] = g_h2[b0 * 1024 + i];
  __syncthreads();
  if (t >= 196) return;
  int j = blockIdx.x * 196 + t;
  float a0 = b3[j], a1 = a0;
#pragma unroll 8
  for (int k = 0; k < 1024; k++) {
    float wv = w3[(size_t)k * 784 + j];
    a0 = fmaf(h_s[0][k], wv, a0);
    a1 = fmaf(h_s[1][k], wv, a1);
  }
  out[2560 + b0 * 784 + j] = 1.f / (1.f + __expf(-a0));
  out[2560 + (b0 + 1) * 784 + j] = 1.f / (1.f + __expf(-a1));
}

// ---------------------------------------------------------------------------
extern "C" void kernel_launch(void* const* d_in, const int* in_sizes, int n_in,
                              void* d_out, int out_size, void* d_ws,
                              size_t ws_size, hipStream_t stream) {
  const float* inputs = (const float*)d_in[0];
  const int* labels = (const int*)d_in[1];
  const float* conv1_w = (const float*)d_in[2];
  const float* conv1_b = (const float*)d_in[3];
  const float* pc_w = (const float*)d_in[4];
  const float* pc_b = (const float*)d_in[5];
  const float* rw = (const float*)d_in[6];
  const float* dw1 = (const float*)d_in[7];
  const float* db1 = (const float*)d_in[8];
  const float* dw2 = (const float*)d_in[9];
  const float* db2 = (const float*)d_in[10];
  const float* dw3 = (const float*)d_in[11];
  const float* db3 = (const float*)d_in[12];
  float* out = (float*)d_out;
  (void)d_ws; (void)ws_size; (void)in_sizes; (void)n_in;

  zero_ssum_k<<<(3 * 256 * 160 + 255) / 256, 256, 0, stream>>>();
  wconv_k<<<dim3(16, 32), 256, 0, stream>>>(pc_w);
  wb1_k<<<96, 256, 0, stream>>>(conv1_w);
  im2col_k<<<dim3(256, 2), 256, 0, stream>>>(inputs);
  conv1_mfma_k<<<1600, 256, 0, stream>>>(conv1_b);
  pc_mfma_k<<<dim3(144, KSPLIT), 512, 0, stream>>>();
  squash_u_k<<<9216, 256, 0, stream>>>(pc_b);
  wu_k<<<dim3(1152, 8), 256, 0, stream>>>(rw);
  red0_k<<<dim3(256, 8), 256, 0, stream>>>();
  routing_iter_k<1><<<dim3(256, 8), 256, 0, stream>>>();
  routing_iter_k<2><<<dim3(256, 8), 256, 0, stream>>>();
  dec1_k<<<dim3(2, 256), 256, 0, stream>>>(labels, dw1, db1, out);
  dec2_k<<<dim3(4, 128), 256, 0, stream>>>(dw2, db2);
  dec3_k<<<dim3(4, 128), 256, 0, stream>>>(dw3, db3, out);
}

// Round 16
// 453.710 us; speedup vs baseline: 1.0752x; 1.0461x over previous
//
#include <hip/hip_runtime.h>
#include <math.h>

// ---------------------------------------------------------------------------
// CapsuleNet forward. R35: tail consolidation.
//  (a) prep_k: zero_ssum + wconv + wb1 + im2col (mutually independent) merged
//      into one kernel via blockIdx.x range partition (1600 blocks); LDS
//      aliased through one 41.5KB buffer. 14 -> 11 launches (saves 3 gaps).
//  (b) wu_k: thread -> (bl=t>>3, 20 consecutive cds) mapping; 5 x bf16x4
//      8B stores per thread (contiguous 2560B/wave), kills the div/mod loop
//      and 15 store instrs/thread. W_s stride-20 access = conflict-free.
// pc_mfma_k frozen at R28 best (105us). Everything else identical to R34
// (474.6us best).
// ---------------------------------------------------------------------------

typedef unsigned short u16;
typedef short bf16x8 __attribute__((ext_vector_type(8)));
typedef short bf16x4 __attribute__((ext_vector_type(4)));
typedef float f32x4 __attribute__((ext_vector_type(4)));

#define PS 2359296   // 9216*256, one y2 partial buffer
#define KSPLIT 9
#define KSLICE 2304  // 20736/9
#define NSTG2 18     // 2304/128

__device__ u16 g_x1b[256 * 400 * 256];          // conv1 out NHWC bf16 (52 MB)
__device__ u16 g_wbF[648 * 16 * 512];           // pc_w bf16, MFMA frag order (10.6 MB)
__device__ u16 g_y2p[(size_t)KSPLIT * PS];      // pc GEMM K-partials bf16 (42.5 MB)
__device__ u16 g_ub[256 * 1152 * 8];            // squashed primary caps bf16 (18.9 MB)
__device__ u16 g_WU[(size_t)256 * 1152 * 160];  // u_hat bf16 (94.4 MB)
__device__ float g_ssum[3 * 256 * 160];
__device__ float g_h1[256 * 512];
__device__ float g_h2[256 * 1024];

// conv1-as-GEMM buffers
__device__ __attribute__((aligned(256))) u16 g_im2[(size_t)102400 * 104];  // im2col bf16, 104-padded rows (21.3 MB)
__device__ __attribute__((aligned(256))) u16 g_wb1[48 * 512];              // conv1_w frags (48 KB)

__device__ __forceinline__ u16 f2bf(float f) {
  union { float f; unsigned u; } v; v.f = f;
  unsigned r = (v.u + 0x7FFFu + ((v.u >> 16) & 1u)) >> 16;  // RNE
  return (u16)r;
}
__device__ __forceinline__ float bf2f(u16 h) {
  union { unsigned u; float f; } v; v.u = ((unsigned)h) << 16;
  return v.f;
}

// ---- merged preprocessing: [0,512) wconv | [512,608) wb1 |
//      [608,1120) im2col | [1120,1600) zero_ssum ----
__global__ __launch_bounds__(256) void prep_k(const float* __restrict__ pcw,
                                              const float* __restrict__ c1w,
                                              const float* __restrict__ in) {
  __shared__ float Ws[16 * 648];   // 41.5 KB (aliased by im2col part)
  int bx = blockIdx.x;
  int t = threadIdx.x;

  if (bx < 512) {
    // ---- wconv: pc_w fp32 [oc][ic][kp] -> bf16 16x16 frag order ----
    int n16 = bx >> 5;   // 0..15
    int icb = bx & 31;   // 0..31
    int c = icb >> 2, h = icb & 3;
#pragma unroll
    for (int ocl = 0; ocl < 16; ocl++) {
      const float* src = pcw + (size_t)(n16 * 16 + ocl) * 20736 + icb * 648;
      for (int i = t; i < 648; i += 256) Ws[ocl * 648 + i] = src[i];
    }
    __syncthreads();
    for (int wi = t; wi < 81 * 128; wi += 256) {
      int kp = wi >> 7;
      int r7 = wi & 127;
      int llh = r7 >> 3, j = wi & 7;
      g_wbF[(((size_t)kp * 8 + c) * 16 + n16) * 512 + h * 128 + r7] =
          f2bf(Ws[llh * 648 + j * 81 + kp]);
    }
  } else if (bx < 608) {
    // ---- wb1: conv1_w fp32 [oc][81] -> bf16 B-frag order ----
    int idx = (bx - 512) * 256 + t;   // 0..24575
    int frag = idx >> 9;
    int r = idx & 511;
    int ll = r >> 3, j = r & 7;
    int kc = frag >> 4, n16 = frag & 15;
    int k = kc * 32 + ((ll >> 4) << 3) + j;
    int oc = n16 * 16 + (ll & 15);
    float v = (k < 81) ? c1w[oc * 81 + k] : 0.f;
    g_wb1[idx] = f2bf(v);
  } else if (bx < 1120) {
    // ---- im2col: fp32 [b][28][28] -> bf16 patches [m][104] ----
    u16* im_s = (u16*)Ws;
    int blk = bx - 608;
    int b = blk >> 1;
    int half = blk & 1;
    for (int i = t; i < 784; i += 256) im_s[i] = f2bf(in[b * 784 + i]);
    __syncthreads();
    u16* outp = g_im2 + (size_t)b * 41600;   // 400*104
    int base = half * 2600;
    for (int ii = t; ii < 2600; ii += 256) {
      int idx = base + ii;
      int p = idx / 13;
      int ko = (idx - p * 13) * 8;
      int oy = p / 20, ox = p - oy * 20;
      bf16x8 v;
#pragma unroll
      for (int e = 0; e < 8; e++) {
        int k = ko + e;
        u16 x = 0;
        if (k < 81) {
          int ky = k / 9, kx = k - ky * 9;
          x = im_s[(oy + ky) * 28 + ox + kx];
        }
        v[e] = (short)x;
      }
      *(bf16x8*)(outp + (size_t)p * 104 + ko) = v;
    }
  } else {
    // ---- zero_ssum ----
    int i = (bx - 1120) * 256 + t;
    if (i < 3 * 256 * 160) g_ssum[i] = 0.f;
  }
}

// ------ conv1 as MFMA GEMM: M=102400, N=256, K=96 --------------------------
__global__ __launch_bounds__(256) void conv1_mfma_k(const float* __restrict__ bias) {
  int t = threadIdx.x;
  int wq = t >> 6;          // wave's oc-quarter
  int l = t & 63;
  int q = l >> 4, c15 = l & 15;
  int m0 = blockIdx.x * 64;

  // B fragments: 3 kc x 4 n16 (this wave's quarter)
  bf16x8 bf[3][4];
#pragma unroll
  for (int kc = 0; kc < 3; kc++)
#pragma unroll
    for (int jn = 0; jn < 4; jn++)
      bf[kc][jn] = *(const bf16x8*)&g_wb1[((kc * 16 + wq * 4 + jn) << 9) + l * 8];

  // A fragments: 4 m-tiles x 3 kc
  bf16x8 af[4][3];
#pragma unroll
  for (int mt = 0; mt < 4; mt++) {
    const u16* ap = g_im2 + (size_t)(m0 + mt * 16 + c15) * 104 + q * 8;
#pragma unroll
    for (int kc = 0; kc < 3; kc++)
      af[mt][kc] = *(const bf16x8*)(ap + kc * 32);
  }

  f32x4 acc[4][4];
#pragma unroll
  for (int mt = 0; mt < 4; mt++)
#pragma unroll
    for (int jn = 0; jn < 4; jn++) acc[mt][jn] = (f32x4){0.f, 0.f, 0.f, 0.f};

#pragma unroll
  for (int kc = 0; kc < 3; kc++)
#pragma unroll
    for (int mt = 0; mt < 4; mt++)
#pragma unroll
      for (int jn = 0; jn < 4; jn++)
        acc[mt][jn] = __builtin_amdgcn_mfma_f32_16x16x32_bf16(af[mt][kc], bf[kc][jn], acc[mt][jn], 0, 0, 0);

  float bv[4];
#pragma unroll
  for (int jn = 0; jn < 4; jn++) bv[jn] = bias[wq * 64 + jn * 16 + c15];

#pragma unroll
  for (int mt = 0; mt < 4; mt++) {
#pragma unroll
    for (int rg = 0; rg < 4; rg++) {
      int row = m0 + mt * 16 + q * 4 + rg;
      int b = row / 400;
      int p = row - b * 400;
      u16* ob = g_x1b + (size_t)b * 102400 + p * 256;
#pragma unroll
      for (int jn = 0; jn < 4; jn++) {
        int col = wq * 64 + jn * 16 + c15;
        ob[col] = f2bf(fmaxf(acc[mt][jn][rg] + bv[jn], 0.f));
      }
    }
  }
}

// ---- pc conv: R28 structure, BK=128 as two 64-k halves, 18 stages ---------
__global__ __launch_bounds__(512) void pc_mfma_k() {
  __shared__ u16 As[3 * 8192];  // 3 bufs x (2 halves x 4096 u16) = 48 KB
  int t = threadIdx.x;
  int m0 = blockIdx.x * 64;
  int ks0 = blockIdx.y * KSLICE;
  u16* outp = g_y2p + (size_t)blockIdx.y * PS;

  int w = t >> 6, l = t & 63, quad = l >> 4, c15 = l & 15;

  // A staging (per half, identical to R25): thread t fills physical chunk
  // (t&7) of row (t>>3); content = logical chunk (t&7)^(row&7).
  int sr = t >> 3;
  int sc = t & 7;
  int cch = sc ^ (sr & 7);
  int fixed0;
  {
    int m = m0 + sr;
    int bb = m / 36;
    int s = m - bb * 36;
    int oy = s / 6;
    int ox = s - oy * 6;
    fixed0 = bb * 102400 + oy * 10240 + ox * 512 + cch * 8;
  }

  // B fragments: wave w owns cols [w*32, w*32+32) -> n16 = w*2+jn
  int bofs[2];
#pragma unroll
  for (int jn = 0; jn < 2; jn++) bofs[jn] = ((w * 2 + jn) << 9) + l * 8;

  f32x4 acc[4][2];
#pragma unroll
  for (int i = 0; i < 4; i++)
#pragma unroll
    for (int j = 0; j < 2; j++) acc[i][j] = (f32x4){0.f, 0.f, 0.f, 0.f};

  bf16x8 bpf[4][2];

  // issue stage st's A loads: 2 global_load_lds per wave (one per 64-k half).
  // 128-k window never crosses a kp boundary (k0 mult of 128, 128|256).
  auto STAGE = [&](int st, int buf) {
    int k0 = ks0 + st * 128;
    int kp = k0 >> 8, ic0 = k0 & 255;    // ic0 in {0,128}
    int ky = kp / 9, kx = kp - ky * 9;
    int off = ky * 5120 + kx * 256 + ic0;
    u16* l0 = &As[buf * 8192 + w * 512];          // half 0, wave-uniform base
    u16* l1 = &As[buf * 8192 + 4096 + w * 512];   // half 1
    __builtin_amdgcn_global_load_lds(
        (const __attribute__((address_space(1))) unsigned*)(g_x1b + fixed0 + off),
        (__attribute__((address_space(3))) unsigned*)l0, 16, 0, 0);
    __builtin_amdgcn_global_load_lds(
        (const __attribute__((address_space(1))) unsigned*)(g_x1b + fixed0 + off + 64),
        (__attribute__((address_space(3))) unsigned*)l1, 16, 0, 0);
  };
  // B prefetch for stage st (8 x 16B loads, L2-resident)
  auto BPF = [&](int st) {
    const u16* bp = g_wbF + ((size_t)((ks0 + st * 128) >> 5) << 13);
#pragma unroll
    for (int kc = 0; kc < 4; kc++)
#pragma unroll
      for (int jn = 0; jn < 2; jn++)
        bpf[kc][jn] = *(const bf16x8*)(bp + (kc << 13) + bofs[jn]);
  };
  // 32 MFMA, 16 ds_read_b128 on compile-time buffer index
  auto COMPUTE = [&](int buf) {
#pragma unroll
    for (int h = 0; h < 2; h++) {
#pragma unroll
      for (int kk = 0; kk < 2; kk++) {
#pragma unroll
        for (int i = 0; i < 4; i++) {
          int rr = i * 16 + c15;
          int pch = (kk * 4 + quad) ^ (rr & 7);
          bf16x8 af = *(const bf16x8*)&As[buf * 8192 + h * 4096 + rr * 64 + pch * 8];
#pragma unroll
          for (int jn = 0; jn < 2; jn++)
            acc[i][jn] = __builtin_amdgcn_mfma_f32_16x16x32_bf16(af, bpf[h * 2 + kk][jn], acc[i][jn], 0, 0, 0);
        }
      }
    }
  };

  // prologue: A0, B0, A1 (issue order pinned; A(st) is always oldest)
  STAGE(0, 0);
  asm volatile("" ::: "memory");
  BPF(0);
  asm volatile("" ::: "memory");
  STAGE(1, 1);
  asm volatile("" ::: "memory");

  // main loop: stages 0..14 (5 groups of 3); buffers compile-time via unroll.
  // Window at stage top: A(st)[2] + B(st)[8] + A(st+1)[2] = 12 -> vmcnt(10)
  // retires A(st).
  for (int mst = 0; mst < NSTG2 - 3; mst += 3) {
#pragma unroll
    for (int sub = 0; sub < 3; sub++) {
      int st = mst + sub;
      asm volatile("s_waitcnt vmcnt(10)" ::: "memory");
      __builtin_amdgcn_sched_barrier(0);
      __builtin_amdgcn_s_barrier();   // all A(st) visible; compute(st-1) done
      asm volatile("" ::: "memory");
      STAGE(st + 2, (sub + 2) % 3);   // overwrites buffer read at st-1: safe
      asm volatile("" ::: "memory");
      __builtin_amdgcn_s_setprio(1);
      COMPUTE(sub);                   // buf = st%3 = sub
      __builtin_amdgcn_s_setprio(0);
      BPF(st + 1);
      asm volatile("" ::: "memory");
    }
  }
  // tail: st = 15 (buf 0), 16 (buf 1), 17 (buf 2)
  asm volatile("s_waitcnt vmcnt(10)" ::: "memory");
  __builtin_amdgcn_sched_barrier(0);
  __builtin_amdgcn_s_barrier();
  asm volatile("" ::: "memory");
  STAGE(17, 2);
  asm volatile("" ::: "memory");
  __builtin_amdgcn_s_setprio(1);
  COMPUTE(0);
  __builtin_amdgcn_s_setprio(0);
  BPF(16);
  asm volatile("" ::: "memory");

  asm volatile("s_waitcnt vmcnt(10)" ::: "memory");
  __builtin_amdgcn_sched_barrier(0);
  __builtin_amdgcn_s_barrier();
  asm volatile("" ::: "memory");
  __builtin_amdgcn_s_setprio(1);
  COMPUTE(1);
  __builtin_amdgcn_s_setprio(0);
  BPF(17);
  asm volatile("" ::: "memory");

  asm volatile("s_waitcnt vmcnt(8)" ::: "memory");
  __builtin_amdgcn_sched_barrier(0);
  __builtin_amdgcn_s_barrier();
  asm volatile("" ::: "memory");
  __builtin_amdgcn_s_setprio(1);
  COMPUTE(2);
  __builtin_amdgcn_s_setprio(0);

  // epilogue: C/D map col=lane&15, row=quad*4+reg; wave w -> cols w*32..w*32+31
#pragma unroll
  for (int i = 0; i < 4; i++)
#pragma unroll
    for (int jn = 0; jn < 2; jn++) {
      int col = w * 32 + jn * 16 + c15;
#pragma unroll
      for (int rg = 0; rg < 4; rg++) {
        int row = m0 + i * 16 + quad * 4 + rg;
        outp[(size_t)row * 256 + col] = f2bf(acc[i][jn][rg]);
      }
    }
}

// ---------------- squash primary capsules (bf16 output) --------------------
__global__ __launch_bounds__(256) void squash_u_k(const float* __restrict__ pcb) {
  __shared__ float xs[256];
  __shared__ float scs[32];
  int m = blockIdx.x;          // 0..9215
  int t = threadIdx.x;
  int b = m / 36;
  int s = m - b * 36;
  float x = pcb[t];
  const u16* base = g_y2p + (size_t)m * 256 + t;
#pragma unroll
  for (int q = 0; q < KSPLIT; q++) x += bf2f(base[(size_t)q * PS]);
  xs[t] = x;
  __syncthreads();
  if (t < 32) {
    float sq = 0.f;
#pragma unroll
    for (int p = 0; p < 8; p++) {
      float v = xs[t + p * 32];
      sq = fmaf(v, v, sq);
    }
    scs[t] = (sq / (1.f + sq)) * rsqrtf(sq + 1e-7f);
  }
  __syncthreads();
  int g = t & 31, p = t >> 5;
  g_ub[((size_t)b * 1152 + g * 36 + s) * 8 + p] = f2bf(x * scs[g]);
}

// ---------------- WU einsum (bf16 u input, vectorized bf16 stores) ---------
__global__ __launch_bounds__(256) void wu_k(const float* __restrict__ W) {
  __shared__ float W_s[8][161];
  __shared__ float u_s[32][8];
  int n = blockIdx.x;
  int b0 = blockIdx.y * 32;
  int t = threadIdx.x;
  const float* Wn = W + (size_t)n * 1280;
  for (int i = t; i < 1280; i += 256) {
    int cd = i >> 3, p = i & 7;
    W_s[p][cd] = Wn[i];
  }
  if (t < 32) {
    bf16x8 uv = *(const bf16x8*)&g_ub[(size_t)(b0 + t) * 9216 + n * 8];
#pragma unroll
    for (int e = 0; e < 8; e++) u_s[t][e] = bf2f((u16)uv[e]);
  }
  __syncthreads();
  // thread t -> batch bl = t>>3, 20 consecutive cds at cd0 = (t&7)*20
  int bl = t >> 3, cd0 = (t & 7) * 20;
  float ur[8];
#pragma unroll
  for (int p = 0; p < 8; p++) ur[p] = u_s[bl][p];
  float accv[20];
#pragma unroll
  for (int k = 0; k < 20; k++) accv[k] = 0.f;
#pragma unroll
  for (int p = 0; p < 8; p++) {
    float up = ur[p];
#pragma unroll
    for (int k = 0; k < 20; k++) accv[k] = fmaf(up, W_s[p][cd0 + k], accv[k]);
  }
  u16* orow = g_WU + ((size_t)(b0 + bl) * 1152 + n) * 160 + cd0;
#pragma unroll
  for (int g = 0; g < 5; g++) {
    bf16x4 v;
#pragma unroll
    for (int e = 0; e < 4; e++) v[e] = (short)f2bf(accv[g * 4 + e]);
    *(bf16x4*)(orow + g * 4) = v;   // 8B stores, 8B-aligned (cd0 mult of 20 -> 40B)
  }
}

// ---------------- iter0 reduction (bf16 input) ----------------
__global__ __launch_bounds__(256) void red0_k() {
  int b = blockIdx.x;
  int chunk = blockIdx.y;
  int t = threadIdx.x;
  if (t >= 160) return;
  const u16* base = g_WU + ((size_t)b * 1152 + chunk * 144) * 160 + t;
  float acc = 0.f;
  for (int n = 0; n < 144; n++) acc += bf2f(base[(size_t)n * 160]);
  atomicAdd(&g_ssum[b * 160 + t], 0.1f * acc);
}

// ---------------- routing iteration: lane = class, in-block squash ---------
template <int IT>
__global__ __launch_bounds__(256) void routing_iter_k() {
  __shared__ float red_s[16 * 272];   // [grp][lane*17 + d], 17-padded, 17.4 KB
  int b = blockIdx.x;
  int nb = blockIdx.y;
  int t = threadIdx.x;
  int lane = t & 15;           // class c (0..9 active)
  int grp = t >> 4;            // 0..15, each group handles 9 n's
  bool active = lane < 10;
  int cl = active ? lane : 9;  // clamped for safe (in-bounds) loads

  float v0r[16];
  {
    const float* s0 = g_ssum + b * 160 + cl * 16;
    float sq = 0.f;
#pragma unroll
    for (int d = 0; d < 16; d++) { v0r[d] = s0[d]; sq = fmaf(s0[d], s0[d], sq); }
    float scale = (sq / (1.f + sq)) * rsqrtf(sq + 1e-7f);
#pragma unroll
    for (int d = 0; d < 16; d++) v0r[d] *= scale;
  }
  float v1r[16];
  if (IT == 2) {
    const float* s1 = g_ssum + 40960 + b * 160 + cl * 16;
    float sq = 0.f;
#pragma unroll
    for (int d = 0; d < 16; d++) { v1r[d] = s1[d]; sq = fmaf(s1[d], s1[d], sq); }
    float scale = (sq / (1.f + sq)) * rsqrtf(sq + 1e-7f);
#pragma unroll
    for (int d = 0; d < 16; d++) v1r[d] *= scale;
  }

  float acc[16];
#pragma unroll
  for (int d = 0; d < 16; d++) acc[d] = 0.f;

  float* ssum_out = g_ssum + IT * 40960;

  for (int ni = 0; ni < 9; ni++) {
    int n = nb * 144 + grp * 9 + ni;
    const u16* row = g_WU + ((size_t)b * 1152 + n) * 160 + cl * 16;
    bf16x8 wlo = *(const bf16x8*)row;         // 32B-aligned
    bf16x8 whi = *(const bf16x8*)(row + 8);
    float wu[16];
#pragma unroll
    for (int e = 0; e < 8; e++) {
      wu[e] = bf2f((u16)wlo[e]);
      wu[8 + e] = bf2f((u16)whi[e]);
    }

    // bij = 0.1 * dot(v0[c], wu[c]) — serial in-thread, 2 partial chains
    float s0 = 0.f, s1 = 0.f;
#pragma unroll
    for (int d = 0; d < 8; d++) {
      s0 = fmaf(v0r[d], wu[d], s0);
      s1 = fmaf(v0r[8 + d], wu[8 + d], s1);
    }
    float bij = active ? 0.1f * (s0 + s1) : -3.0e38f;

    // softmax over classes (16-lane group; inactive lanes -> exp = 0)
    float mx = bij;
    mx = fmaxf(mx, __shfl_xor(mx, 1));
    mx = fmaxf(mx, __shfl_xor(mx, 2));
    mx = fmaxf(mx, __shfl_xor(mx, 4));
    mx = fmaxf(mx, __shfl_xor(mx, 8));
    float e = __expf(bij - mx);
    float es = e;
    es += __shfl_xor(es, 1);
    es += __shfl_xor(es, 2);
    es += __shfl_xor(es, 4);
    es += __shfl_xor(es, 8);
    float sm = e / es;

    if (IT == 2) {
      // agreement uses s_ij = c*WU: bij += sm * dot(v1[c], wu[c])
      float q0 = 0.f, q1 = 0.f;
#pragma unroll
      for (int d = 0; d < 8; d++) {
        q0 = fmaf(v1r[d], wu[d], q0);
        q1 = fmaf(v1r[8 + d], wu[8 + d], q1);
      }
      bij = active ? (bij + sm * (q0 + q1)) : -3.0e38f;
      float mx2 = bij;
      mx2 = fmaxf(mx2, __shfl_xor(mx2, 1));
      mx2 = fmaxf(mx2, __shfl_xor(mx2, 2));
      mx2 = fmaxf(mx2, __shfl_xor(mx2, 4));
      mx2 = fmaxf(mx2, __shfl_xor(mx2, 8));
      float e2 = __expf(bij - mx2);
      float es2 = e2;
      es2 += __shfl_xor(es2, 1);
      es2 += __shfl_xor(es2, 2);
      es2 += __shfl_xor(es2, 4);
      es2 += __shfl_xor(es2, 8);
      sm = e2 / es2;
    }

#pragma unroll
    for (int d = 0; d < 16; d++) acc[d] = fmaf(sm, wu[d], acc[d]);
  }

  // block-level reduction: 16 group-partials -> 1 coalesced atomic per output
#pragma unroll
  for (int d = 0; d < 16; d++) red_s[grp * 272 + lane * 17 + d] = acc[d];
  __syncthreads();
  if (t < 160) {
    int c = t >> 4, d = t & 15;
    float tot = 0.f;
#pragma unroll
    for (int g = 0; g < 16; g++) tot += red_s[g * 272 + c * 17 + d];
    atomicAdd(&ssum_out[b * 160 + t], tot);
  }
}

// ---------------- decoder (dec1 computes v[lab] + clf inline) --------------
__global__ __launch_bounds__(256) void dec1_k(const int* __restrict__ labels,
                                              const float* __restrict__ w1,
                                              const float* __restrict__ b1,
                                              float* __restrict__ out) {
  int b = blockIdx.y;
  int j = blockIdx.x * 256 + threadIdx.x;
  int lab = labels[b];
  // v[b][lab] from ssum slot 2 (squash inline; broadcast loads)
  const float* s = g_ssum + 2 * 40960 + b * 160 + lab * 16;
  float vv[16];
  float sq = 0.f;
#pragma unroll
  for (int d = 0; d < 16; d++) { vv[d] = s[d]; sq = fmaf(s[d], s[d], sq); }
  float scale = (sq / (1.f + sq)) * rsqrtf(sq + 1e-7f);
  float acc = b1[j];
#pragma unroll
  for (int d = 0; d < 16; d++)
    acc = fmaf(vv[d] * scale, w1[(size_t)(lab * 16 + d) * 512 + j], acc);
  g_h1[b * 512 + j] = fmaxf(acc, 0.f);

  // clf: block x==0, threads 0..9 write out[b*10+c]
  if (blockIdx.x == 0 && threadIdx.x < 10) {
    int c = threadIdx.x;
    const float* sc = g_ssum + 2 * 40960 + b * 160 + c * 16;
    float sqc = 0.f;
#pragma unroll
    for (int d = 0; d < 16; d++) sqc = fmaf(sc[d], sc[d], sqc);
    float scc = (sqc / (1.f + sqc)) * rsqrtf(sqc + 1e-7f);
    out[b * 10 + c] = scc * sqrtf(sqc);
  }
}

// dec2: 2 batches per block — w2 stream reused 2x. Grid (4, 128).
__global__ __launch_bounds__(256) void dec2_k(const float* __restrict__ w2,
                                              const float* __restrict__ b2) {
  __shared__ float h_s[2][512];
  int b0 = blockIdx.y * 2;
  int j = blockIdx.x * 256 + threadIdx.x;
  int t = threadIdx.x;
  for (int i = t; i < 1024; i += 256) h_s[i >> 9][i & 511] = g_h1[b0 * 512 + i];
  __syncthreads();
  float a0 = b2[j], a1 = a0;
#pragma unroll 8
  for (int k = 0; k < 512; k++) {
    float wv = w2[(size_t)k * 1024 + j];
    a0 = fmaf(h_s[0][k], wv, a0);
    a1 = fmaf(h_s[1][k], wv, a1);
  }
  g_h2[b0 * 1024 + j] = fmaxf(a0, 0.f);
  g_h2[(b0 + 1) * 1024 + j] = fmaxf(a1, 0.f);
}

// dec3: 2 batches per block — w3 stream reused 2x. Grid (4, 128).
__global__ __launch_bounds__(256) void dec3_k(const float* __restrict__ w3,
                                              const float* __restrict__ b3,
                                              float* __restrict__ out) {
  __shared__ float h_s[2][1024];
  int b0 = blockIdx.y * 2;
  int t = threadIdx.x;
  for (int i = t; i < 2048; i += 256) h_s[i >> 10][i & 1023] = g_h2[b0 * 1024 + i];
  __syncthreads();
  if (t >= 196) return;
  int j = blockIdx.x * 196 + t;
  float a0 = b3[j], a1 = a0;
#pragma unroll 8
  for (int k = 0; k < 1024; k++) {
    float wv = w3[(size_t)k * 784 + j];
    a0 = fmaf(h_s[0][k], wv, a0);
    a1 = fmaf(h_s[1][k], wv, a1);
  }
  out[2560 + b0 * 784 + j] = 1.f / (1.f + __expf(-a0));
  out[2560 + (b0 + 1) * 784 + j] = 1.f / (1.f + __expf(-a1));
}

// ---------------------------------------------------------------------------
extern "C" void kernel_launch(void* const* d_in, const int* in_sizes, int n_in,
                              void* d_out, int out_size, void* d_ws,
                              size_t ws_size, hipStream_t stream) {
  const float* inputs = (const float*)d_in[0];
  const int* labels = (const int*)d_in[1];
  const float* conv1_w = (const float*)d_in[2];
  const float* conv1_b = (const float*)d_in[3];
  const float* pc_w = (const float*)d_in[4];
  const float* pc_b = (const float*)d_in[5];
  const float* rw = (const float*)d_in[6];
  const float* dw1 = (const float*)d_in[7];
  const float* db1 = (const float*)d_in[8];
  const float* dw2 = (const float*)d_in[9];
  const float* db2 = (const float*)d_in[10];
  const float* dw3 = (const float*)d_in[11];
  const float* db3 = (const float*)d_in[12];
  float* out = (float*)d_out;
  (void)d_ws; (void)ws_size; (void)in_sizes; (void)n_in;

  prep_k<<<1600, 256, 0, stream>>>(pc_w, conv1_w, inputs);
  conv1_mfma_k<<<1600, 256, 0, stream>>>(conv1_b);
  pc_mfma_k<<<dim3(144, KSPLIT), 512, 0, stream>>>();
  squash_u_k<<<9216, 256, 0, stream>>>(pc_b);
  wu_k<<<dim3(1152, 8), 256, 0, stream>>>(rw);
  red0_k<<<dim3(256, 8), 256, 0, stream>>>();
  routing_iter_k<1><<<dim3(256, 8), 256, 0, stream>>>();
  routing_iter_k<2><<<dim3(256, 8), 256, 0, stream>>>();
  dec1_k<<<dim3(2, 256), 256, 0, stream>>>(labels, dw1, db1, out);
  dec2_k<<<dim3(4, 128), 256, 0, stream>>>(dw2, db2);
  dec3_k<<<dim3(4, 128), 256, 0, stream>>>(dw3, db3, out);
}